// Round 9
// baseline (113.186 us; speedup 1.0000x reference)
//
#include <hip/hip_runtime.h>
#include <hip/hip_bf16.h>
#include <math.h>

#define BATCH 8
#define NPTS 4096
#define CH 128
#define CTG 8                         // column strips per batch (512 cols each)
#define ROWS 128                      // rows per block (mi=2: bfrag reuse x2)
#define CHUNK 32                      // columns per chunk
#define NCHUNK (NPTS / (CTG * CHUNK)) // 16 chunks per block
#define NBUF 6                        // ring: 2 chunks/body, staged 2 pairs ahead

// exp(s/TEMP) = 2^(s * 10 * log2(e)). sqrt(10/ln2) is folded into the
// normalize scale so the GEMM accumulator is already the exp2 argument.
#define SQRT_TEMP_LOG2E 3.79828256f   // sqrt(14.4269504089)

typedef __attribute__((ext_vector_type(4))) float    f32x4;
typedef __attribute__((ext_vector_type(4))) int      i32x4;
typedef __attribute__((ext_vector_type(8))) short    bf16x8;
typedef __attribute__((ext_vector_type(4))) _Float16 f16x4;

typedef __attribute__((address_space(3))) unsigned int lds_uint;
typedef __attribute__((address_space(1))) const unsigned int gbl_uint;

__device__ __forceinline__ void load_lds16(const void* g, const void* l) {
    __builtin_amdgcn_global_load_lds((gbl_uint*)g, (lds_uint*)l, 16, 0, 0);
}

__device__ __forceinline__ float fast_exp2(float x) {
    return __builtin_amdgcn_exp2f(x);
}

// 16x16x16 f16 MFMA (K=16). Its A/B input layout (row=lane&15, k=quad*4+j)
// matches the C/D layout of the main 16x16x32 GEMM — chained MFMAs need no
// cross-lane data movement.
__device__ __forceinline__ f32x4 mfma16(f16x4 a, f16x4 b, f32x4 c) {
#if __has_builtin(__builtin_amdgcn_mfma_f32_16x16x16f16)
    return __builtin_amdgcn_mfma_f32_16x16x16f16(a, b, c, 0, 0, 0);
#else
    f32x4 d = c;
    asm volatile("v_mfma_f32_16x16x16_f16 %0, %1, %2, %0"
                 : "+v"(d) : "v"(a), "v"(b));
    return d;
#endif
}

// ---------------------------------------------------------------------------
// Kernel 1: coalesced two-pass L2-normalize. R8 post-mortem: the 8-threads/
// point layout read 32B segments (3x the 4us BW floor) because the in-wave
// shfl reduce forced q to be the fast index. This version: block = 64 points,
// lane = point (pass-1 reads are 256B-coalesced), 4-way LDS tree for ||v||^2,
// pass-2 re-read is L1-hot (32KB block working set), bf16 packed into a 16KB
// LDS tile with 16B-chunk XOR swizzle (<=2-way bank aliasing = free), then
// streamed out contiguously (1KB per store instruction).
// ---------------------------------------------------------------------------
__global__ __launch_bounds__(256) void normalize_kernel(
    const float* __restrict__ f, __hip_bfloat16* __restrict__ vn,
    float* __restrict__ pos, float* __restrict__ neg, float* __restrict__ out)
{
    const int blk = blockIdx.x;            // 512 blocks
    const int b = blk >> 6;                // 64 blocks per batch
    const int n0 = (blk & 63) * 64;        // 64 points per block
    const int nl = threadIdx.x & 63;       // point lane
    const int cg = threadIdx.x >> 6;       // channel quarter (32 ch)
    const float* base = f + (size_t)b * CH * NPTS + (size_t)(cg * 32) * NPTS
                          + n0 + nl;

    __shared__ float red[4][64];
    __shared__ float scl[64];
    __shared__ short ostage[64 * CH];      // 16 KB staging tile

    // pass 1: sum of squares (fully coalesced 256B segments per instruction)
    float ss = 0.0f;
    #pragma unroll
    for (int c = 0; c < 32; c++) {
        float v = base[(size_t)c * NPTS];
        ss += v * v;
    }
    red[cg][nl] = ss;
    __syncthreads();
    if (cg == 0) {
        float s = red[0][nl] + red[1][nl] + red[2][nl] + red[3][nl];
        scl[nl] = SQRT_TEMP_LOG2E / fmaxf(sqrtf(s), 1e-12f);
    }
    __syncthreads();
    const float scale = scl[nl];

    // pass 2: re-read (L1-hot), convert, stage swizzled 16B chunks.
    // logical chunk (pt, ch8) -> physical chunk pt*16 + (ch8 ^ (pt&15)).
    #pragma unroll
    for (int k = 0; k < 4; k++) {
        union { __hip_bfloat16 h[8]; uint4 u; } pk;
        #pragma unroll
        for (int j = 0; j < 8; j++) {
            float v = base[(size_t)(k * 8 + j) * NPTS] * scale;
            pk.h[j] = __float2bfloat16(v);
        }
        const int ch8 = cg * 4 + k;
        const int phys = (nl << 4) | (ch8 ^ (nl & 15));
        *(uint4*)&ostage[phys * 8] = pk.u;
    }
    __syncthreads();

    // cooperative contiguous write: 4 x 256 threads x 16B = 16 KB
    __hip_bfloat16* ob = vn + ((size_t)b * NPTS + n0) * CH;
    const int t = threadIdx.x;
    #pragma unroll
    for (int it = 0; it < 4; it++) {
        const int L = it * 256 + t;        // logical chunk 0..1023
        const int pt = L >> 4, c8 = L & 15;
        const int phys = (pt << 4) | (c8 ^ (pt & 15));
        *(uint4*)(ob + (size_t)L * 8) = *(const uint4*)&ostage[phys * 8];
    }

    if (cg == 0) pos[b * NPTS + n0 + nl] = 0.0f;
    else if (cg == 1) neg[b * NPTS + n0 + nl] = 0.0f;
    if (blk == 0 && t == 0) out[0] = 0.0f;
}

// ---------------------------------------------------------------------------
// Kernel 2: persistent column-strip GEMM, PAIR-BODIES (2 chunks / barrier).
//
// R8 post-mortem: residency levers failed twice (occupancy 30->33%, time
// flat) — the residual ~25us of dual-pipe idle is the 16 barrier+vmcnt
// rounds per block. This version halves syncs: 8 pair-bodies, each
//   [ bar | MFMA(2P->accA) | EPI(2P-1,accB) | MFMA(2P+1->accB)
//     | stage(2P+4) stage(2P+5) | EPI(2P,accA) | vmcnt(4) ]
// NBUF=6 chunk ring (48KB) + 2KB labels = 50KB -> 3 blocks/CU (residency
// demonstrably wasn't the lever; the 2x ILP window per barrier is).
//
// Counted-vmcnt proof (4 vm ops per body, EXACTLY two 2-op stages):
//  - end of body P-1: vmcnt(4) leaves only pair P+1's 4 ops in flight =>
//    pair P (chunks 2P,2P+1) retired before bar(P) releases its reads.
//  - overwrite: body P stages chunks 2P+4,2P+5 -> bufs (2P+4)%6,(2P+5)%6 =
//    the bufs read during body P-1, whose ds_reads were lgkm-consumed before
//    each wave reached bar(P).
//  - EPI(2P-1) reads accB BEFORE MFMA(2P+1) overwrites it (program order,
//    register dependence — compiler preserves).
//  - prologue: labels(1) + afrag/lr(10) + chunks 0..3 (8 ops); vmcnt(4)
//    before body 0 keeps only chunks 2,3 => chunks 0,1 + labels retired.
// Bodies P=0..7; P6/P7 stage dead chunks (&15 -> 0..3, harmless: target
// bufs are never read again). Post-loop: EPI(15, accB).
//
// Swapped operands: mfma(bfrag, afrag, acc) => acc[mi][ni] elem (lane,r) =
//   S[row0 + w*32 + mi*16 + lane15][colbase + chunk*32 + ni*16 + quad*4 + r]
// Class-GEMM epilogue (labels in [0,16)): qout[mi] elem (lane,r) =
//   q[class=quad*4+r, row=lane15] accumulated in the MFMA pipe;
//   p = q[l_row] - diag, tt = sum_k q[k] - diag.
// launch_bounds(256,4): 128-reg unified cap (R7 lesson: AGPRs count; (256,6)
// spilled catastrophically). R8 measured 64 arch VGPR — unchanged body shape.
// ---------------------------------------------------------------------------
__global__ __launch_bounds__(256, 4) void tile_kernel(
    const __hip_bfloat16* __restrict__ vn, const int* __restrict__ labels,
    float* __restrict__ pos, float* __restrict__ neg)
{
    __shared__ short lB[NBUF][CHUNK * CH];   // 6 x 8 KB ring
    __shared__ int labL[NPTS / CTG];         // 512 column labels of strip

    const int ctg = blockIdx.x, rt = blockIdx.y, b = blockIdx.z;
    const int tid = threadIdx.x;
    const int w = tid >> 6, lane = tid & 63;
    const int lane15 = lane & 15, quad = lane >> 4;

    const int row0 = rt * ROWS;
    const int colbase = ctg * (NPTS / CTG);
    const __hip_bfloat16* vb = vn + (size_t)b * NPTS * CH;
    const int* labb = labels + b * NPTS;

    // Stage one 32-col chunk -> ring buffer. XOR chunk swizzle at the global
    // source (LDS dest order is HW-fixed: wave-uniform base + lane*16B).
    // 4 waves x 2 iters x 4 rows. 0 bank conflicts (proven swizzle).
    auto stage = [&](int buf, int chunk) {
        const __hip_bfloat16* Bb = vb + (size_t)(colbase + chunk * CHUNK) * CH;
        #pragma unroll
        for (int i = 0; i < 2; i++) {
            int ldsrow = w * 8 + i * 4;             // wave-uniform
            int r = ldsrow + quad;                  // row this lane feeds
            int g = lane15 ^ (r & 15);              // swizzled global chunk
            load_lds16(Bb + (size_t)r * CH + g * 8, &lB[buf][ldsrow * CH]);
        }
    };

    // ---- prologue. vm order: labels(1) -> afrag+lr(10) -> chunks 0..3 (8).
    load_lds16(labb + colbase + (w & 1) * 256 + lane * 4, &labL[(w & 1) * 256]);

    bf16x8 afrag[2][4];
    int lr[2];
    #pragma unroll
    for (int mi = 0; mi < 2; mi++) {
        const int row_l = w * 32 + mi * 16 + lane15;
        const __hip_bfloat16* Arow = vb + (size_t)(row0 + row_l) * CH;
        #pragma unroll
        for (int ks = 0; ks < 4; ks++)
            afrag[mi][ks] = *(const bf16x8*)(Arow + (ks * 4 + quad) * 8);
        lr[mi] = labb[row0 + row_l];
    }

    stage(0, 0);
    stage(1, 1);
    stage(2, 2);
    stage(3, 3);

    // Hoisted LDS byte offsets within a chunk buffer (8 VGPRs).
    int vad[2][4];
    #pragma unroll
    for (int ni = 0; ni < 2; ni++)
        #pragma unroll
        for (int ks = 0; ks < 4; ks++)
            vad[ni][ks] = (((ni * 16 + lane15) * CH) +
                           (((ks * 4 + quad) ^ lane15) << 3)) * 2;

    f32x4 qout[2] = {{0.0f, 0.0f, 0.0f, 0.0f}, {0.0f, 0.0f, 0.0f, 0.0f}};
    float ddiag[2] = {0.0f, 0.0f};
    const f32x4 zf = {0.0f, 0.0f, 0.0f, 0.0f};
    f32x4 accA[2][2], accB[2][2];

#define MFMA_PH(BUF_, ACC_)                                                   \
    {                                                                         \
        _Pragma("unroll")                                                     \
        for (int ni = 0; ni < 2; ni++) {                                      \
            bf16x8 bf = *(const bf16x8*)((const char*)(&lB[0][0]) +           \
                         (BUF_) * (CHUNK * CH * 2) + vad[ni][0]);             \
            ACC_[0][ni] = __builtin_amdgcn_mfma_f32_16x16x32_bf16(            \
                bf, afrag[0][0], zf, 0, 0, 0);                                \
            ACC_[1][ni] = __builtin_amdgcn_mfma_f32_16x16x32_bf16(            \
                bf, afrag[1][0], zf, 0, 0, 0);                                \
        }                                                                     \
        _Pragma("unroll")                                                     \
        for (int ks = 1; ks < 4; ks++) {                                      \
            _Pragma("unroll")                                                 \
            for (int ni = 0; ni < 2; ni++) {                                  \
                bf16x8 bf = *(const bf16x8*)((const char*)(&lB[0][0]) +       \
                             (BUF_) * (CHUNK * CH * 2) + vad[ni][ks]);        \
                ACC_[0][ni] = __builtin_amdgcn_mfma_f32_16x16x32_bf16(        \
                    bf, afrag[0][ks], ACC_[0][ni], 0, 0, 0);                  \
                ACC_[1][ni] = __builtin_amdgcn_mfma_f32_16x16x32_bf16(        \
                    bf, afrag[1][ks], ACC_[1][ni], 0, 0, 0);                  \
            }                                                                 \
        }                                                                     \
    }

#define EPI_PH(EC_, ACC_)                                                     \
    {                                                                         \
        _Pragma("unroll")                                                     \
        for (int ni = 0; ni < 2; ni++) {                                      \
            const i32x4 lc = *(const i32x4*)&labL[(EC_) * CHUNK + ni * 16 +   \
                                                  quad * 4];                  \
            f16x4 oh;                                                         \
            _Pragma("unroll")                                                 \
            for (int j = 0; j < 4; j++)                                       \
                oh[j] = (lc[j] == lane15) ? (_Float16)1.0f : (_Float16)0.0f;  \
            const int colblk = colbase + (EC_) * CHUNK + ni * 16;             \
            _Pragma("unroll")                                                 \
            for (int mi = 0; mi < 2; mi++) {                                  \
                f16x4 eh;                                                     \
                _Pragma("unroll")                                             \
                for (int r = 0; r < 4; r++)                                   \
                    eh[r] = (_Float16)fast_exp2(ACC_[mi][ni][r]);             \
                if (colblk == row0 + w * 32 + mi * 16) {  /* wave-uniform */  \
                    _Pragma("unroll")                                         \
                    for (int r = 0; r < 4; r++)                               \
                        if (lane15 == quad * 4 + r)                           \
                            ddiag[mi] += (float)eh[r];                        \
                }                                                             \
                qout[mi] = mfma16(oh, eh, qout[mi]);                          \
            }                                                                 \
        }                                                                     \
    }

// Pair-body P: bufs BA_=(2P)%6, BB_=(2P+1)%6 (compile-time).
#define PBODY(P_, BA_, BB_, DOEPI_)                                           \
    {                                                                         \
        __builtin_amdgcn_s_barrier();                                         \
        __builtin_amdgcn_s_setprio(1);                                        \
        MFMA_PH(BA_, accA);                                                   \
        __builtin_amdgcn_s_setprio(0);                                        \
        if (DOEPI_) { EPI_PH(2 * (P_) - 1, accB); }                           \
        __builtin_amdgcn_s_setprio(1);                                        \
        MFMA_PH(BB_, accB);                                                   \
        __builtin_amdgcn_s_setprio(0);                                        \
        stage(((BA_) + 4) % 6, (2 * (P_) + 4) & (NCHUNK - 1));                \
        stage(((BB_) + 4) % 6, (2 * (P_) + 5) & (NCHUNK - 1));                \
        EPI_PH(2 * (P_), accA);                                               \
        asm volatile("s_waitcnt vmcnt(4)" ::: "memory");                      \
    }

    asm volatile("s_waitcnt vmcnt(4)" ::: "memory");   // chunks 0,1 ready
    PBODY(0, 0, 1, 0);
    #pragma unroll 1
    for (int p = 1; p <= 4; p += 3) {    // p = 1, 4 -> bodies 1..6
        PBODY(p + 0, 2, 3, 1);
        PBODY(p + 1, 4, 5, 1);
        PBODY(p + 2, 0, 1, 1);
    }
    PBODY(7, 2, 3, 1);                   // stages dead chunks (bufs 0,1 dead)
    EPI_PH(15, accB);                    // final chunk's epilogue

#undef PBODY
#undef EPI_PH
#undef MFMA_PH

    // ---- strip done. qout[mi] elem (lane,r) = q[class=quad*4+r, row=lane15].
    #pragma unroll
    for (int mi = 0; mi < 2; mi++) {
        float p = -ddiag[mi], tt = -ddiag[mi];
        #pragma unroll
        for (int r = 0; r < 4; r++) {
            float v = qout[mi][r];
            tt += v;
            p  += (quad * 4 + r == lr[mi]) ? v : 0.0f;
        }
        p  += __shfl_xor(p, 16);   p  += __shfl_xor(p, 32);
        tt += __shfl_xor(tt, 16);  tt += __shfl_xor(tt, 32);
        if (lane < 16) {
            const int row_l = w * 32 + mi * 16 + lane15;
            atomicAdd(&pos[b * NPTS + row0 + row_l], p);
            atomicAdd(&neg[b * NPTS + row0 + row_l], tt - p);
        }
    }
}

// ---------------------------------------------------------------------------
// Kernel 3: mean of log((p+n)/p) over 32768 rows. 32 blocks x 256 threads;
// out zeroed by normalize_kernel, stream order makes the atomic safe.
// ---------------------------------------------------------------------------
__global__ __launch_bounds__(256) void finalize_kernel(
    const float* __restrict__ pos, const float* __restrict__ neg,
    float* __restrict__ out)
{
    int base = blockIdx.x * 1024 + threadIdx.x;
    float acc = 0.0f;
    #pragma unroll
    for (int k = 0; k < 4; k++) {
        int i = base + k * 256;
        float p = pos[i];
        float t = p + neg[i];
        acc += __logf(t / p);   // == -log(p / (p+n))
    }
    #pragma unroll
    for (int off = 32; off; off >>= 1) acc += __shfl_down(acc, off);
    __shared__ float red[4];
    if ((threadIdx.x & 63) == 0) red[threadIdx.x >> 6] = acc;
    __syncthreads();
    if (threadIdx.x == 0) {
        float v = red[0] + red[1] + red[2] + red[3];
        atomicAdd(out, v * (1.0f / (BATCH * NPTS)));
    }
}

extern "C" void kernel_launch(void* const* d_in, const int* in_sizes, int n_in,
                              void* d_out, int out_size, void* d_ws, size_t ws_size,
                              hipStream_t stream)
{
    const float* features = (const float*)d_in[0];
    const int*   labels   = (const int*)d_in[1];
    float*       out      = (float*)d_out;

    // Workspace: vn bf16 [8][4096][128] = 8 MB, then pos/neg fp32.
    __hip_bfloat16* vn = (__hip_bfloat16*)d_ws;
    float* pos = (float*)((char*)d_ws + (size_t)BATCH * NPTS * CH * sizeof(__hip_bfloat16));
    float* neg = pos + BATCH * NPTS;

    // 512 blocks x 64 points, coalesced two-pass normalize.
    hipLaunchKernelGGL(normalize_kernel, dim3(512), dim3(256), 0, stream,
                       features, vn, pos, neg, out);
    // 128-row x 512-col strips: 8 ctg x 32 rt x 8 batches = 2048 blocks;
    // LDS 50KB -> 3 resident blocks/CU, 8 pair-bodies each.
    hipLaunchKernelGGL(tile_kernel, dim3(CTG, NPTS / ROWS, BATCH), dim3(256), 0, stream,
                       vn, labels, pos, neg);
    hipLaunchKernelGGL(finalize_kernel, dim3(32), dim3(256), 0, stream, pos, neg, out);
}

// Round 10
// 110.603 us; speedup vs baseline: 1.0234x; 1.0234x over previous
//
#include <hip/hip_runtime.h>
#include <hip/hip_bf16.h>
#include <math.h>

#define BATCH 8
#define NPTS 4096
#define CH 128
#define CTG 4                         // column strips per batch (1024 cols each)
#define ROWS 128                      // rows per block (mi=2: bfrag reuse x2)
#define CHUNK 32                      // columns staged per pipeline step
#define NCHUNK (NPTS / (CTG * CHUNK)) // 32 chunks per block
#define NBUF 3                        // ring, staged 2 ahead

// exp(s/TEMP) = 2^(s * 10 * log2(e)). sqrt(10/ln2) is folded into the
// normalize scale so the GEMM accumulator is already the exp2 argument.
#define SQRT_TEMP_LOG2E 3.79828256f   // sqrt(14.4269504089)

typedef __attribute__((ext_vector_type(4))) float    f32x4;
typedef __attribute__((ext_vector_type(4))) int      i32x4;
typedef __attribute__((ext_vector_type(8))) short    bf16x8;
typedef __attribute__((ext_vector_type(4))) _Float16 f16x4;

typedef __attribute__((address_space(3))) unsigned int lds_uint;
typedef __attribute__((address_space(1))) const unsigned int gbl_uint;

__device__ __forceinline__ void load_lds16(const void* g, const void* l) {
    __builtin_amdgcn_global_load_lds((gbl_uint*)g, (lds_uint*)l, 16, 0, 0);
}

__device__ __forceinline__ float fast_exp2(float x) {
    return __builtin_amdgcn_exp2f(x);
}

// 16x16x16 f16 MFMA (K=16). Its A/B input layout (row=lane&15, k=quad*4+j)
// matches the C/D layout of the main 16x16x32 GEMM — chained MFMAs need no
// cross-lane data movement.
__device__ __forceinline__ f32x4 mfma16(f16x4 a, f16x4 b, f32x4 c) {
#if __has_builtin(__builtin_amdgcn_mfma_f32_16x16x16f16)
    return __builtin_amdgcn_mfma_f32_16x16x16f16(a, b, c, 0, 0, 0);
#else
    f32x4 d = c;
    asm volatile("v_mfma_f32_16x16x16_f16 %0, %1, %2, %0"
                 : "+v"(d) : "v"(a), "v"(b));
    return d;
#endif
}

// ---------------------------------------------------------------------------
// Kernel 1: coalesced two-pass L2-normalize (R9, verified: saved ~2.5us vs
// the 8-threads/point layout). Block = 64 points, lane = point: pass-1 reads
// are 256B-coalesced; 4-way LDS tree for ||v||^2; pass-2 re-read is L1-hot
// (32KB block working set); bf16 packed into a 16KB LDS tile with 16B-chunk
// XOR swizzle (<=2-way bank aliasing = free), then streamed out contiguously.
// ---------------------------------------------------------------------------
__global__ __launch_bounds__(256) void normalize_kernel(
    const float* __restrict__ f, __hip_bfloat16* __restrict__ vn,
    float* __restrict__ pos, float* __restrict__ neg, float* __restrict__ out)
{
    const int blk = blockIdx.x;            // 512 blocks
    const int b = blk >> 6;                // 64 blocks per batch
    const int n0 = (blk & 63) * 64;        // 64 points per block
    const int nl = threadIdx.x & 63;       // point lane
    const int cg = threadIdx.x >> 6;       // channel quarter (32 ch)
    const float* base = f + (size_t)b * CH * NPTS + (size_t)(cg * 32) * NPTS
                          + n0 + nl;

    __shared__ float red[4][64];
    __shared__ float scl[64];
    __shared__ short ostage[64 * CH];      // 16 KB staging tile

    // pass 1: sum of squares (fully coalesced 256B segments per instruction)
    float ss = 0.0f;
    #pragma unroll
    for (int c = 0; c < 32; c++) {
        float v = base[(size_t)c * NPTS];
        ss += v * v;
    }
    red[cg][nl] = ss;
    __syncthreads();
    if (cg == 0) {
        float s = red[0][nl] + red[1][nl] + red[2][nl] + red[3][nl];
        scl[nl] = SQRT_TEMP_LOG2E / fmaxf(sqrtf(s), 1e-12f);
    }
    __syncthreads();
    const float scale = scl[nl];

    // pass 2: re-read (L1-hot), convert, stage swizzled 16B chunks.
    // logical chunk (pt, ch8) -> physical chunk pt*16 + (ch8 ^ (pt&15)).
    #pragma unroll
    for (int k = 0; k < 4; k++) {
        union { __hip_bfloat16 h[8]; uint4 u; } pk;
        #pragma unroll
        for (int j = 0; j < 8; j++) {
            float v = base[(size_t)(k * 8 + j) * NPTS] * scale;
            pk.h[j] = __float2bfloat16(v);
        }
        const int ch8 = cg * 4 + k;
        const int phys = (nl << 4) | (ch8 ^ (nl & 15));
        *(uint4*)&ostage[phys * 8] = pk.u;
    }
    __syncthreads();

    // cooperative contiguous write: 4 x 256 threads x 16B = 16 KB
    __hip_bfloat16* ob = vn + ((size_t)b * NPTS + n0) * CH;
    const int t = threadIdx.x;
    #pragma unroll
    for (int it = 0; it < 4; it++) {
        const int L = it * 256 + t;        // logical chunk 0..1023
        const int pt = L >> 4, c8 = L & 15;
        const int phys = (pt << 4) | (c8 ^ (pt & 15));
        *(uint4*)(ob + (size_t)L * 8) = *(const uint4*)&ostage[phys * 8];
    }

    if (cg == 0) pos[b * NPTS + n0 + nl] = 0.0f;
    else if (cg == 1) neg[b * NPTS + n0 + nl] = 0.0f;
    if (blk == 0 && t == 0) out[0] = 0.0f;
}

// ---------------------------------------------------------------------------
// Kernel 2: persistent column-strip GEMM — R5-EXACT config (measured 46.0us
// three times: the best of every structural variant tried R5..R9).
//
// Config record (all measured, tile-only us):
//   R5: CTG=4 NBUF=3 1-chunk bodies vmcnt(2) (256,4)  -> 46.0   <== this
//   R8: CTG=8 (2048 blocks, 5/CU)                     -> 48.1
//   R9: pair-bodies NBUF=6 (3/CU)                     -> 52.8
//   R6: ROWS=64 (no mi reuse)                         -> 57.9
//   R7: (256,6) reg cap 85 -> ACC SPILL               -> 198
// Conclusion: scheduling/residency variants are plateaued at ~46; the pipes
// report Mfma ~36% + VALU ~45% with ~half the issue slots idle in barrier/
// vmcnt convoy, and no sync/TLP trade has beaten this point.
//
// NEXT LEVER (documented for the follow-up round): exp(S/T) is SYMMETRIC.
// Computing only tiles with col_block <= rt and accumulating each strict-
// below-diagonal chunk into BOTH row sums (as today) and col sums (fragment
// transpose via 4x ds_bpermute + masked quad-fold reduce, flushed through
// LDS col-accumulators) halves main-MFMA+exp work (~10us of pipe time) for
// ~4us of added VALU + col atomics. Diagonal 128-blocks stay as today.
//
// Pipeline per body (32 bodies): [ bar | setprio(1) | MFMA(chunk c, buf c%3
// -> accCUR) | setprio(0) | STAGE(chunk c+2 -> buf (c+2)%3) | EPI(chunk c-1,
// accPRV) | s_waitcnt vmcnt(2) ].
//  - read-validity: vmcnt(2) at end of body c-1 leaves only chunk c+1's 2
//    ops in flight => chunk c retired before bar(c).
//  - overwrite-safety: STAGE at body c writes buf (c+2)%3 == buf (c-1)%3,
//    whose ds_reads were lgkm-consumed before each wave reached bar(c).
//  - EXACTLY one STAGE (2 vm ops) per body; no other vm ops in the loop
//    (spill tripwire: WRITE_SIZE; (256,4) => 128-reg unified cap, AGPRs
//    count against it — R7 lesson).
//
// Swapped operands: mfma(bfrag, afrag, acc) => acc[mi][ni] elem (lane,r) =
//   S[row0 + w*32 + mi*16 + lane15][colbase + chunk*32 + ni*16 + quad*4 + r]
// Class-GEMM epilogue (labels in [0,16)): qout[mi] elem (lane,r) =
//   q[class=quad*4+r, row=lane15] accumulated in the MFMA pipe;
//   p = q[l_row] - diag, tt = sum_k q[k] - diag.
// ---------------------------------------------------------------------------
__global__ __launch_bounds__(256, 4) void tile_kernel(
    const __hip_bfloat16* __restrict__ vn, const int* __restrict__ labels,
    float* __restrict__ pos, float* __restrict__ neg)
{
    __shared__ short lB[NBUF][CHUNK * CH];   // 3 x 8 KB ring
    __shared__ int labL[NPTS / CTG];         // 1024 column labels of strip

    const int ctg = blockIdx.x, rt = blockIdx.y, b = blockIdx.z;
    const int tid = threadIdx.x;
    const int w = tid >> 6, lane = tid & 63;
    const int lane15 = lane & 15, quad = lane >> 4;

    const int row0 = rt * ROWS;
    const int colbase = ctg * (NPTS / CTG);
    const __hip_bfloat16* vb = vn + (size_t)b * NPTS * CH;
    const int* labb = labels + b * NPTS;

    // Stage one 32-col chunk -> ring buffer. XOR chunk swizzle at the global
    // source (LDS dest order is HW-fixed: wave-uniform base + lane*16B).
    // 4 waves x 2 iters x 4 rows. 0 bank conflicts (proven swizzle).
    auto stage = [&](int buf, int chunk) {
        const __hip_bfloat16* Bb = vb + (size_t)(colbase + chunk * CHUNK) * CH;
        #pragma unroll
        for (int i = 0; i < 2; i++) {
            int ldsrow = w * 8 + i * 4;             // wave-uniform
            int r = ldsrow + quad;                  // row this lane feeds
            int g = lane15 ^ (r & 15);              // swizzled global chunk
            load_lds16(Bb + (size_t)r * CH + g * 8, &lB[buf][ldsrow * CH]);
        }
    };

    // ---- prologue. vm issue order: labels(1) -> afrag+lr(10) -> chunks 0,1.
    load_lds16(labb + colbase + w * 256 + lane * 4, &labL[w * 256]);

    bf16x8 afrag[2][4];
    int lr[2];
    #pragma unroll
    for (int mi = 0; mi < 2; mi++) {
        const int row_l = w * 32 + mi * 16 + lane15;
        const __hip_bfloat16* Arow = vb + (size_t)(row0 + row_l) * CH;
        #pragma unroll
        for (int ks = 0; ks < 4; ks++)
            afrag[mi][ks] = *(const bf16x8*)(Arow + (ks * 4 + quad) * 8);
        lr[mi] = labb[row0 + row_l];
    }

    stage(0, 0);
    stage(1, 1);

    // Hoisted LDS byte offsets within a chunk buffer (8 VGPRs).
    int vad[2][4];
    #pragma unroll
    for (int ni = 0; ni < 2; ni++)
        #pragma unroll
        for (int ks = 0; ks < 4; ks++)
            vad[ni][ks] = (((ni * 16 + lane15) * CH) +
                           (((ks * 4 + quad) ^ lane15) << 3)) * 2;

    f32x4 qout[2] = {{0.0f, 0.0f, 0.0f, 0.0f}, {0.0f, 0.0f, 0.0f, 0.0f}};
    float ddiag[2] = {0.0f, 0.0f};
    const f32x4 zf = {0.0f, 0.0f, 0.0f, 0.0f};
    f32x4 accA[2][2], accB[2][2];

#define MFMA_PH(BUF_, ACC_)                                                   \
    {                                                                         \
        _Pragma("unroll")                                                     \
        for (int ni = 0; ni < 2; ni++) {                                      \
            bf16x8 bf = *(const bf16x8*)((const char*)(&lB[0][0]) +           \
                         (BUF_) * (CHUNK * CH * 2) + vad[ni][0]);             \
            ACC_[0][ni] = __builtin_amdgcn_mfma_f32_16x16x32_bf16(            \
                bf, afrag[0][0], zf, 0, 0, 0);                                \
            ACC_[1][ni] = __builtin_amdgcn_mfma_f32_16x16x32_bf16(            \
                bf, afrag[1][0], zf, 0, 0, 0);                                \
        }                                                                     \
        _Pragma("unroll")                                                     \
        for (int ks = 1; ks < 4; ks++) {                                      \
            _Pragma("unroll")                                                 \
            for (int ni = 0; ni < 2; ni++) {                                  \
                bf16x8 bf = *(const bf16x8*)((const char*)(&lB[0][0]) +       \
                             (BUF_) * (CHUNK * CH * 2) + vad[ni][ks]);        \
                ACC_[0][ni] = __builtin_amdgcn_mfma_f32_16x16x32_bf16(        \
                    bf, afrag[0][ks], ACC_[0][ni], 0, 0, 0);                  \
                ACC_[1][ni] = __builtin_amdgcn_mfma_f32_16x16x32_bf16(        \
                    bf, afrag[1][ks], ACC_[1][ni], 0, 0, 0);                  \
            }                                                                 \
        }                                                                     \
    }

#define EPI_PH(EC_, ACC_)                                                     \
    {                                                                         \
        _Pragma("unroll")                                                     \
        for (int ni = 0; ni < 2; ni++) {                                      \
            const i32x4 lc = *(const i32x4*)&labL[(EC_) * CHUNK + ni * 16 +   \
                                                  quad * 4];                  \
            f16x4 oh;                                                         \
            _Pragma("unroll")                                                 \
            for (int j = 0; j < 4; j++)                                       \
                oh[j] = (lc[j] == lane15) ? (_Float16)1.0f : (_Float16)0.0f;  \
            const int colblk = colbase + (EC_) * CHUNK + ni * 16;             \
            _Pragma("unroll")                                                 \
            for (int mi = 0; mi < 2; mi++) {                                  \
                f16x4 eh;                                                     \
                _Pragma("unroll")                                             \
                for (int r = 0; r < 4; r++)                                   \
                    eh[r] = (_Float16)fast_exp2(ACC_[mi][ni][r]);             \
                if (colblk == row0 + w * 32 + mi * 16) {  /* wave-uniform */  \
                    _Pragma("unroll")                                         \
                    for (int r = 0; r < 4; r++)                               \
                        if (lane15 == quad * 4 + r)                           \
                            ddiag[mi] += (float)eh[r];                        \
                }                                                             \
                qout[mi] = mfma16(oh, eh, qout[mi]);                          \
            }                                                                 \
        }                                                                     \
    }

#define BODY(C_, BUF_, CUR_, PRV_, DOEPI_)                                    \
    {                                                                         \
        __builtin_amdgcn_s_barrier();                                         \
        __builtin_amdgcn_s_setprio(1);                                        \
        MFMA_PH(BUF_, CUR_);                                                  \
        __builtin_amdgcn_s_setprio(0);                                        \
        stage(((BUF_) + 2) % 3, ((C_) + 2) & (NCHUNK - 1));                   \
        if (DOEPI_) { EPI_PH((C_) - 1, PRV_); }                               \
        asm volatile("s_waitcnt vmcnt(2)" ::: "memory");                      \
    }

    asm volatile("s_waitcnt vmcnt(2)" ::: "memory");   // chunk 0 ready
    BODY(0, 0, accA, accB, 0);
    // bodies 1..30: buf period 3, acc ping-pong period 2 -> 6-groups.
    #pragma unroll 1
    for (int c = 1; c <= 25; c += 6) {       // c = 1, 7, 13, 19, 25
        BODY(c + 0, 1, accB, accA, 1);
        BODY(c + 1, 2, accA, accB, 1);
        BODY(c + 2, 0, accB, accA, 1);
        BODY(c + 3, 1, accA, accB, 1);
        BODY(c + 4, 2, accB, accA, 1);
        BODY(c + 5, 0, accA, accB, 1);
    }
    // body 31: buf 31%3 = 1, no stage / no trailing wait.
    __builtin_amdgcn_s_barrier();
    __builtin_amdgcn_s_setprio(1);
    MFMA_PH(1, accB);
    __builtin_amdgcn_s_setprio(0);
    EPI_PH(30, accA);
    EPI_PH(31, accB);

#undef BODY
#undef EPI_PH
#undef MFMA_PH

    // ---- strip done. qout[mi] elem (lane,r) = q[class=quad*4+r, row=lane15].
    #pragma unroll
    for (int mi = 0; mi < 2; mi++) {
        float p = -ddiag[mi], tt = -ddiag[mi];
        #pragma unroll
        for (int r = 0; r < 4; r++) {
            float v = qout[mi][r];
            tt += v;
            p  += (quad * 4 + r == lr[mi]) ? v : 0.0f;
        }
        p  += __shfl_xor(p, 16);   p  += __shfl_xor(p, 32);
        tt += __shfl_xor(tt, 16);  tt += __shfl_xor(tt, 32);
        if (lane < 16) {
            const int row_l = w * 32 + mi * 16 + lane15;
            atomicAdd(&pos[b * NPTS + row0 + row_l], p);
            atomicAdd(&neg[b * NPTS + row0 + row_l], tt - p);
        }
    }
}

// ---------------------------------------------------------------------------
// Kernel 3: mean of log((p+n)/p) over 32768 rows. 32 blocks x 256 threads;
// out zeroed by normalize_kernel, stream order makes the atomic safe.
// ---------------------------------------------------------------------------
__global__ __launch_bounds__(256) void finalize_kernel(
    const float* __restrict__ pos, const float* __restrict__ neg,
    float* __restrict__ out)
{
    int base = blockIdx.x * 1024 + threadIdx.x;
    float acc = 0.0f;
    #pragma unroll
    for (int k = 0; k < 4; k++) {
        int i = base + k * 256;
        float p = pos[i];
        float t = p + neg[i];
        acc += __logf(t / p);   // == -log(p / (p+n))
    }
    #pragma unroll
    for (int off = 32; off; off >>= 1) acc += __shfl_down(acc, off);
    __shared__ float red[4];
    if ((threadIdx.x & 63) == 0) red[threadIdx.x >> 6] = acc;
    __syncthreads();
    if (threadIdx.x == 0) {
        float v = red[0] + red[1] + red[2] + red[3];
        atomicAdd(out, v * (1.0f / (BATCH * NPTS)));
    }
}

extern "C" void kernel_launch(void* const* d_in, const int* in_sizes, int n_in,
                              void* d_out, int out_size, void* d_ws, size_t ws_size,
                              hipStream_t stream)
{
    const float* features = (const float*)d_in[0];
    const int*   labels   = (const int*)d_in[1];
    float*       out      = (float*)d_out;

    // Workspace: vn bf16 [8][4096][128] = 8 MB, then pos/neg fp32.
    __hip_bfloat16* vn = (__hip_bfloat16*)d_ws;
    float* pos = (float*)((char*)d_ws + (size_t)BATCH * NPTS * CH * sizeof(__hip_bfloat16));
    float* neg = pos + BATCH * NPTS;

    // 512 blocks x 64 points, coalesced two-pass normalize (R9, verified).
    hipLaunchKernelGGL(normalize_kernel, dim3(512), dim3(256), 0, stream,
                       features, vn, pos, neg, out);
    // R5-exact strip grid: 4 ctg x 32 rt x 8 batches = 1024 blocks, 4/CU.
    hipLaunchKernelGGL(tile_kernel, dim3(CTG, NPTS / ROWS, BATCH), dim3(256), 0, stream,
                       vn, labels, pos, neg);
    hipLaunchKernelGGL(finalize_kernel, dim3(32), dim3(256), 0, stream, pos, neg, out);
}